// Round 1
// baseline (1361.173 us; speedup 1.0000x reference)
//
#include <hip/hip_runtime.h>
#include <hip/hip_bf16.h>

#define N_NODES 100000
#define N_EDGES 1600000
#define ETOT    (N_EDGES + N_NODES)   // edges + self loops = 1,700,000
#define NF      256
#define NG      512
#define NHC     64                    // H*C
#define NOUT3   192                   // 3 views * 64
#define BN_EPS  1e-5f

__device__ __forceinline__ unsigned fenc(float f){
  unsigned b = __float_as_uint(f);
  return (b & 0x80000000u) ? ~b : (b | 0x80000000u);
}
__device__ __forceinline__ float fdec(unsigned u){
  unsigned b = (u & 0x80000000u) ? (u & 0x7FFFFFFFu) : ~u;
  return __uint_as_float(b);
}
__device__ __forceinline__ float lrelu(float x){ return x > 0.f ? x : 0.2f * x; }
__device__ __forceinline__ float eluf(float x){ return x > 0.f ? x : (__expf(x) - 1.f); }

// ---------------- init pooled to encoded -inf ----------------
__global__ void k_init_pooled(unsigned* pooled){
  int i = blockIdx.x * 256 + threadIdx.x;
  if (i < 3 * NG * NHC) pooled[i] = 0x007FFFFFu;   // fenc(-inf)
}

// ---------------- column stats of x ----------------
__global__ __launch_bounds__(256) void k_stats(const float* __restrict__ x,
                                               float* __restrict__ sums,
                                               float* __restrict__ sumsq){
  int t = threadIdx.x;
  int r0 = blockIdx.x * 128;
  int rmax = N_NODES - r0; if (rmax > 128) rmax = 128;
  float s = 0.f, q = 0.f;
  for (int r = 0; r < rmax; ++r){
    float v = x[(size_t)(r0 + r) * NF + t];
    s += v; q += v * v;
  }
  atomicAdd(&sums[t], s);
  atomicAdd(&sumsq[t], q);
}

// ---------------- fold BN into combined weight W' (256x192) and bias b' ----------------
__global__ __launch_bounds__(256) void k_prep(const float* __restrict__ sums, const float* __restrict__ sumsq,
                                              const float* __restrict__ bn_w, const float* __restrict__ bn_b,
                                              const float* __restrict__ WA, const float* __restrict__ WC,
                                              const float* __restrict__ WP,
                                              float* __restrict__ Wp, float* __restrict__ bp){
  __shared__ float ssc[NF], ssh[NF];
  int t = threadIdx.x;
  float mu  = sums[t]  * (1.f / N_NODES);
  float var = sumsq[t] * (1.f / N_NODES) - mu * mu;
  float sc  = bn_w[t] * rsqrtf(var + BN_EPS);
  ssc[t] = sc;
  ssh[t] = bn_b[t] - mu * sc;
  __syncthreads();
  if (t < NOUT3){
    int v = t / 64, o = t % 64;
    const float* W = (v == 0) ? WA : (v == 1) ? WC : WP;
    float b = 0.f;
    for (int f = 0; f < NF; ++f){
      float w = W[f * 64 + o];
      Wp[f * NOUT3 + t] = w * ssc[f];
      b += ssh[f] * w;
    }
    bp[t] = b;
  }
}

// ---------------- h_all = x @ W' + b'   (M=100000, K=256, N=192) ----------------
#define BM 128
#define BN 192
#define BK 32
__global__ __launch_bounds__(256) void k_gemm(const float* __restrict__ x, const float* __restrict__ Wp,
                                              const float* __restrict__ bp, float* __restrict__ h_all){
  __shared__ float xs[BK][BM];
  __shared__ float ws_[BK][BN];
  int t = threadIdx.x;
  int m0 = blockIdx.x * BM;
  int tc = (t & 15) * 12;
  int tr = (t >> 4) * 8;
  float acc[8][12];
#pragma unroll
  for (int i = 0; i < 8; ++i)
#pragma unroll
    for (int j = 0; j < 12; ++j) acc[i][j] = 0.f;

  int lrow = t >> 1;
  int lkh  = (t & 1) * 16;
  int grow = m0 + lrow; if (grow >= N_NODES) grow = N_NODES - 1;
  int wrow = t >> 3;
  int wc4  = (t & 7) * 6;

  for (int kc = 0; kc < NF; kc += BK){
    const float4* xsrc = (const float4*)(x + (size_t)grow * NF + kc + lkh);
    float4 a0 = xsrc[0], a1 = xsrc[1], a2 = xsrc[2], a3 = xsrc[3];
    const float4* wsrc = (const float4*)(Wp + (size_t)(kc + wrow) * BN);
    float4 b0 = wsrc[wc4+0], b1 = wsrc[wc4+1], b2 = wsrc[wc4+2],
           b3 = wsrc[wc4+3], b4 = wsrc[wc4+4], b5 = wsrc[wc4+5];
    __syncthreads();   // previous compute done before overwrite
    xs[lkh+ 0][lrow]=a0.x; xs[lkh+ 1][lrow]=a0.y; xs[lkh+ 2][lrow]=a0.z; xs[lkh+ 3][lrow]=a0.w;
    xs[lkh+ 4][lrow]=a1.x; xs[lkh+ 5][lrow]=a1.y; xs[lkh+ 6][lrow]=a1.z; xs[lkh+ 7][lrow]=a1.w;
    xs[lkh+ 8][lrow]=a2.x; xs[lkh+ 9][lrow]=a2.y; xs[lkh+10][lrow]=a2.z; xs[lkh+11][lrow]=a2.w;
    xs[lkh+12][lrow]=a3.x; xs[lkh+13][lrow]=a3.y; xs[lkh+14][lrow]=a3.z; xs[lkh+15][lrow]=a3.w;
    float4* wdst = (float4*)&ws_[wrow][0];
    wdst[wc4+0]=b0; wdst[wc4+1]=b1; wdst[wc4+2]=b2; wdst[wc4+3]=b3; wdst[wc4+4]=b4; wdst[wc4+5]=b5;
    __syncthreads();
#pragma unroll
    for (int k = 0; k < BK; ++k){
      float xv[8], wv[12];
      *(float4*)&xv[0] = *(const float4*)&xs[k][tr];
      *(float4*)&xv[4] = *(const float4*)&xs[k][tr+4];
      *(float4*)&wv[0] = *(const float4*)&ws_[k][tc];
      *(float4*)&wv[4] = *(const float4*)&ws_[k][tc+4];
      *(float4*)&wv[8] = *(const float4*)&ws_[k][tc+8];
#pragma unroll
      for (int i2 = 0; i2 < 8; ++i2)
#pragma unroll
        for (int j2 = 0; j2 < 12; ++j2)
          acc[i2][j2] += xv[i2] * wv[j2];
    }
  }
#pragma unroll
  for (int i2 = 0; i2 < 8; ++i2){
    int gr = m0 + tr + i2;
    if (gr < N_NODES){
      float* dst = h_all + (size_t)gr * BN + tc;
#pragma unroll
      for (int j2 = 0; j2 < 12; ++j2) dst[j2] = acc[i2][j2] + bp[tc + j2];
    }
  }
}

// ---------------- per (node,view,head) attention logits ----------------
__global__ __launch_bounds__(256) void k_att(const float* __restrict__ h_all,
                                             const float* __restrict__ asA, const float* __restrict__ adA,
                                             const float* __restrict__ asC, const float* __restrict__ adC,
                                             const float* __restrict__ asP, const float* __restrict__ adP,
                                             float* __restrict__ a_src, float* __restrict__ a_dst){
  int t = blockIdx.x * 256 + threadIdx.x;
  int g = t >> 4; int lid = t & 15;
  if (g >= 3 * N_NODES) return;
  int v = g / N_NODES; int n = g - v * N_NODES;
  const float* As = (v == 0) ? asA : (v == 1) ? asC : asP;
  const float* Ad = (v == 0) ? adA : (v == 1) ? adC : adP;
  float4 hv = *(const float4*)(h_all + (size_t)n * NOUT3 + v * 64 + lid * 4);
  float4 s4 = *(const float4*)(As + lid * 4);
  float4 d4 = *(const float4*)(Ad + lid * 4);
  float rs = hv.x*s4.x + hv.y*s4.y + hv.z*s4.z + hv.w*s4.w;
  float rd = hv.x*d4.x + hv.y*d4.y + hv.z*d4.z + hv.w*d4.w;
  rs += __shfl_xor(rs, 1); rd += __shfl_xor(rd, 1);
  rs += __shfl_xor(rs, 2); rd += __shfl_xor(rd, 2);
  rs += __shfl_xor(rs, 4); rd += __shfl_xor(rd, 4);
  if ((lid & 7) == 0){
    int h = lid >> 3;
    a_src[g * 2 + h] = rs;
    a_dst[g * 2 + h] = rd;
  }
}

// ---------------- per-edge: segment max (encoded) + dst histogram ----------------
__global__ __launch_bounds__(256) void k_edge1(const int* __restrict__ eA, const int* __restrict__ eC,
                                               const int* __restrict__ eP,
                                               const float* __restrict__ a_src, const float* __restrict__ a_dst,
                                               unsigned* __restrict__ mvec, int* __restrict__ count){
  int i = blockIdx.x * 256 + threadIdx.x;
  if (i >= 3 * ETOT) return;
  int v = i / ETOT; int j = i - v * ETOT;
  const int* ei = (v == 0) ? eA : (v == 1) ? eC : eP;
  int s, d;
  if (j < N_EDGES){ s = ei[j]; d = ei[N_EDGES + j]; } else { s = j - N_EDGES; d = s; }
  int vs = v * N_NODES + s, vd = v * N_NODES + d;
  float e0 = lrelu(a_src[vs*2+0] + a_dst[vd*2+0]);
  float e1 = lrelu(a_src[vs*2+1] + a_dst[vd*2+1]);
  atomicMax(&mvec[vd*2+0], fenc(e0));
  atomicMax(&mvec[vd*2+1], fenc(e1));
  atomicAdd(&count[vd], 1);
}

// ---------------- exclusive scan (3 phases) ----------------
__global__ __launch_bounds__(256) void k_scan1(const int* __restrict__ cnt, int* __restrict__ out,
                                               int* __restrict__ bsum, int n){
  __shared__ int sh[256];
  int t = threadIdx.x; int base = blockIdx.x * 1024 + t * 4;
  int v0 = (base+0 < n) ? cnt[base+0] : 0;
  int v1 = (base+1 < n) ? cnt[base+1] : 0;
  int v2 = (base+2 < n) ? cnt[base+2] : 0;
  int v3 = (base+3 < n) ? cnt[base+3] : 0;
  int s = v0 + v1 + v2 + v3;
  sh[t] = s; __syncthreads();
  for (int off = 1; off < 256; off <<= 1){
    int xv = (t >= off) ? sh[t - off] : 0;
    __syncthreads();
    sh[t] += xv;
    __syncthreads();
  }
  int p = sh[t] - s;
  if (t == 255) bsum[blockIdx.x] = sh[255];
  if (base+0 < n){ out[base+0] = p; p += v0; }
  if (base+1 < n){ out[base+1] = p; p += v1; }
  if (base+2 < n){ out[base+2] = p; p += v2; }
  if (base+3 < n){ out[base+3] = p; }
}

__global__ __launch_bounds__(512) void k_scan2(int* __restrict__ bsum, int* __restrict__ total_out, int nb){
  __shared__ int sh[512];
  int t = threadIdx.x;
  int o = (t < nb) ? bsum[t] : 0;
  sh[t] = o; __syncthreads();
  for (int off = 1; off < 512; off <<= 1){
    int xv = (t >= off) ? sh[t - off] : 0;
    __syncthreads();
    sh[t] += xv;
    __syncthreads();
  }
  if (t < nb) bsum[t] = sh[t] - o;
  if (t == nb - 1) total_out[0] = sh[t];
}

__global__ __launch_bounds__(256) void k_scan3(int* __restrict__ out, const int* __restrict__ bsum, int n){
  int add = bsum[blockIdx.x];
  int base = blockIdx.x * 1024 + threadIdx.x * 4;
  if (base+0 < n) out[base+0] += add;
  if (base+1 < n) out[base+1] += add;
  if (base+2 < n) out[base+2] += add;
  if (base+3 < n) out[base+3] += add;
}

// ---------------- CSR scatter of src ids ----------------
__global__ __launch_bounds__(256) void k_scatter(const int* __restrict__ eA, const int* __restrict__ eC,
                                                 const int* __restrict__ eP,
                                                 const int* __restrict__ offsets, int* __restrict__ fill,
                                                 int* __restrict__ entries){
  int i = blockIdx.x * 256 + threadIdx.x;
  if (i >= 3 * ETOT) return;
  int v = i / ETOT; int j = i - v * ETOT;
  const int* ei = (v == 0) ? eA : (v == 1) ? eC : eP;
  int s, d;
  if (j < N_EDGES){ s = ei[j]; d = ei[N_EDGES + j]; } else { s = j - N_EDGES; d = s; }
  int vd = v * N_NODES + d;
  int pos = offsets[vd] + atomicAdd(&fill[vd], 1);
  entries[pos] = s;
}

// ---------------- gather: softmax-weighted aggregate + elu + graph max-pool ----------------
__global__ __launch_bounds__(256) void k_gather(const int* __restrict__ entries, const int* __restrict__ offsets,
                                                const unsigned* __restrict__ mvec,
                                                const float* __restrict__ a_src, const float* __restrict__ a_dst,
                                                const float* __restrict__ h_all,
                                                const float* __restrict__ bA, const float* __restrict__ bC,
                                                const float* __restrict__ bP,
                                                const int* __restrict__ batch, unsigned* __restrict__ pooled){
  __shared__ unsigned red[64];
  __shared__ int kmin, kmax;
  int t = threadIdx.x;
  if (t == 0){ kmin = 0x7FFFFFFF; kmax = -1; }
  if (t < 64) red[t] = 0u;
  __syncthreads();
  // grid is exact: 3N/16 blocks, every g valid
  int g = blockIdx.x * 16 + (t >> 4);
  int lid = t & 15;
  int v = g / N_NODES; int n = g - v * N_NODES;
  float ad0 = a_dst[g*2+0], ad1 = a_dst[g*2+1];
  float m0 = fdec(mvec[g*2+0]), m1 = fdec(mvec[g*2+1]);
  int beg = offsets[g], end = offsets[g+1];
  float ax = 0.f, ay = 0.f, az = 0.f, aw = 0.f;
  float den0 = 0.f, den1 = 0.f;
  const float* hbase = h_all + v * 64 + lid * 4;
  int vN = v * N_NODES;
  for (int j = beg; j < end; ++j){
    int s = entries[j];
    const float* ap = a_src + (size_t)(vN + s) * 2;
    float p0 = __expf(lrelu(ap[0] + ad0) - m0);
    float p1 = __expf(lrelu(ap[1] + ad1) - m1);
    den0 += p0; den1 += p1;
    float4 hv = *(const float4*)(hbase + (size_t)s * NOUT3);
    float ph = (lid < 8) ? p0 : p1;
    ax += ph * hv.x; ay += ph * hv.y; az += ph * hv.z; aw += ph * hv.w;
  }
  float den = ((lid < 8) ? den0 : den1) + 1e-16f;
  const float* bias = (v == 0) ? bA : (v == 1) ? bC : bP;
  float4 b4 = *(const float4*)(bias + lid * 4);
  unsigned e0 = fenc(eluf(ax / den + b4.x));
  unsigned e1 = fenc(eluf(ay / den + b4.y));
  unsigned e2 = fenc(eluf(az / den + b4.z));
  unsigned e3 = fenc(eluf(aw / den + b4.w));
  int key = v * NG + batch[n];
  if (lid == 0){ atomicMin(&kmin, key); atomicMax(&kmax, key); }
  atomicMax(&red[lid*4+0], e0); atomicMax(&red[lid*4+1], e1);
  atomicMax(&red[lid*4+2], e2); atomicMax(&red[lid*4+3], e3);
  __syncthreads();
  if (kmin == kmax){
    if (t < 64) atomicMax(&pooled[(size_t)kmin * 64 + t], red[t]);
  } else {
    unsigned* pp = pooled + (size_t)key * 64 + lid * 4;
    atomicMax(pp+0, e0); atomicMax(pp+1, e1); atomicMax(pp+2, e2); atomicMax(pp+3, e3);
  }
}

// ---------------- head MLP: one wave per graph ----------------
__global__ __launch_bounds__(64) void k_head(const unsigned* __restrict__ pooled,
                                             const float* __restrict__ g1w, const float* __restrict__ g1b,
                                             const float* __restrict__ g2w, const float* __restrict__ g2b,
                                             const float* __restrict__ c1w, const float* __restrict__ c1b,
                                             const float* __restrict__ c2w, const float* __restrict__ c2b,
                                             const float* __restrict__ c3w, const float* __restrict__ c3b,
                                             float* __restrict__ out){
  __shared__ float s1[64];
  __shared__ float s2[128];
  __shared__ float sw[3];
  int g = blockIdx.x, l = threadIdx.x;
  float ha = fdec(pooled[(size_t)g * 64 + l]);
  float hc = fdec(pooled[(size_t)(NG + g) * 64 + l]);
  float hp = fdec(pooled[(size_t)(2 * NG + g) * 64 + l]);
  s1[l] = (ha + hc + hp) * (1.f / 3.f);
  __syncthreads();
  float r1 = 0.f;
  if (l < 32){
    r1 = g1b[l];
    for (int i = 0; i < 64; ++i) r1 += s1[i] * g1w[i * 32 + l];
    r1 = fmaxf(r1, 0.f);
  }
  __syncthreads();
  if (l < 32) s2[l] = r1;
  __syncthreads();
  if (l < 3){
    float tv = g2b[l];
    for (int i = 0; i < 32; ++i) tv += s2[i] * g2w[i * 3 + l];
    sw[l] = tv;
  }
  __syncthreads();
  float t0 = sw[0], t1 = sw[1], t2 = sw[2];
  float mx = fmaxf(t0, fmaxf(t1, t2));
  float w0 = __expf(t0 - mx), w1 = __expf(t1 - mx), w2 = __expf(t2 - mx);
  float wsum = w0 + w1 + w2;
  float fused = (w0 * ha + w1 * hc + w2 * hp) / wsum;
  __syncthreads();
  s1[l] = fused;
  __syncthreads();
  float za = c1b[l], zb = c1b[64 + l];
  for (int i = 0; i < 64; ++i){
    float f = s1[i];
    za += f * c1w[i * 128 + l];
    zb += f * c1w[i * 128 + 64 + l];
  }
  za = fmaxf(za, 0.f); zb = fmaxf(zb, 0.f);
  s2[l] = za; s2[64 + l] = zb;
  __syncthreads();
  float z2 = c2b[l];
  for (int i = 0; i < 128; ++i) z2 += s2[i] * c2w[i * 64 + l];
  z2 = fmaxf(z2, 0.f);
  float prod = z2 * c3w[l];
  for (int off = 32; off > 0; off >>= 1) prod += __shfl_down(prod, off);
  if (l == 0) out[g] = prod + c3b[0];
}

extern "C" void kernel_launch(void* const* d_in, const int* in_sizes, int n_in,
                              void* d_out, int out_size, void* d_ws, size_t ws_size,
                              hipStream_t stream){
  const float* x    = (const float*)d_in[0];
  const int* eA     = (const int*)d_in[1];
  const int* eC     = (const int*)d_in[2];
  const int* eP     = (const int*)d_in[3];
  const int* batch  = (const int*)d_in[4];
  const float* bn_w = (const float*)d_in[6];
  const float* bn_b = (const float*)d_in[7];
  const float* WA   = (const float*)d_in[8];
  const float* asA  = (const float*)d_in[9];
  const float* adA  = (const float*)d_in[10];
  const float* bA   = (const float*)d_in[11];
  const float* WC   = (const float*)d_in[12];
  const float* asC  = (const float*)d_in[13];
  const float* adC  = (const float*)d_in[14];
  const float* bC   = (const float*)d_in[15];
  const float* WP   = (const float*)d_in[16];
  const float* asP  = (const float*)d_in[17];
  const float* adP  = (const float*)d_in[18];
  const float* bP   = (const float*)d_in[19];
  const float* g1w  = (const float*)d_in[20];
  const float* g1b  = (const float*)d_in[21];
  const float* g2w  = (const float*)d_in[22];
  const float* g2b  = (const float*)d_in[23];
  const float* c1w  = (const float*)d_in[24];
  const float* c1b  = (const float*)d_in[25];
  const float* c2w  = (const float*)d_in[26];
  const float* c2b  = (const float*)d_in[27];
  const float* c3w  = (const float*)d_in[28];
  const float* c3b  = (const float*)d_in[29];
  float* out = (float*)d_out;

  char* wptr = (char*)d_ws;
  auto alloc = [&](size_t bytes) -> void* {
    void* p = (void*)wptr;
    wptr += (bytes + 255) & ~(size_t)255;
    return p;
  };
  float*    sums    = (float*)   alloc((size_t)NF * 4);
  float*    sumsq   = (float*)   alloc((size_t)NF * 4);
  unsigned* mvec    = (unsigned*)alloc((size_t)3 * N_NODES * 2 * 4);
  int*      count   = (int*)     alloc((size_t)3 * N_NODES * 4);
  int*      fill    = (int*)     alloc((size_t)3 * N_NODES * 4);
  size_t zbytes = (size_t)(wptr - (char*)sums);          // contiguous zero region
  int*      offsets = (int*)     alloc(((size_t)3 * N_NODES + 1) * 4);
  float*    Wp      = (float*)   alloc((size_t)NF * NOUT3 * 4);
  float*    bp      = (float*)   alloc((size_t)NOUT3 * 4);
  float*    h_all   = (float*)   alloc((size_t)N_NODES * NOUT3 * 4);
  float*    a_src   = (float*)   alloc((size_t)3 * N_NODES * 2 * 4);
  float*    a_dst   = (float*)   alloc((size_t)3 * N_NODES * 2 * 4);
  int*      entries = (int*)     alloc((size_t)3 * ETOT * 4);
  unsigned* pooled  = (unsigned*)alloc((size_t)3 * NG * NHC * 4);
  int*      bsum    = (int*)     alloc((size_t)1024 * 4);

  hipMemsetAsync(sums, 0, zbytes, stream);
  k_init_pooled<<<(3 * NG * NHC + 255) / 256, 256, 0, stream>>>(pooled);
  k_stats<<<(N_NODES + 127) / 128, 256, 0, stream>>>(x, sums, sumsq);
  k_prep<<<1, 256, 0, stream>>>(sums, sumsq, bn_w, bn_b, WA, WC, WP, Wp, bp);
  k_gemm<<<(N_NODES + BM - 1) / BM, 256, 0, stream>>>(x, Wp, bp, h_all);
  k_att<<<(3 * N_NODES * 16 + 255) / 256, 256, 0, stream>>>(h_all, asA, adA, asC, adC, asP, adP, a_src, a_dst);
  k_edge1<<<(3 * ETOT + 255) / 256, 256, 0, stream>>>(eA, eC, eP, a_src, a_dst, mvec, count);
  int n3 = 3 * N_NODES;
  int nb = (n3 + 1023) / 1024;
  k_scan1<<<nb, 256, 0, stream>>>(count, offsets, bsum, n3);
  k_scan2<<<1, 512, 0, stream>>>(bsum, offsets + n3, nb);
  k_scan3<<<nb, 256, 0, stream>>>(offsets, bsum, n3);
  k_scatter<<<(3 * ETOT + 255) / 256, 256, 0, stream>>>(eA, eC, eP, offsets, fill, entries);
  k_gather<<<n3 / 16, 256, 0, stream>>>(entries, offsets, mvec, a_src, a_dst, h_all, bA, bC, bP, batch, pooled);
  k_head<<<NG, 64, 0, stream>>>(pooled, g1w, g1b, g2w, g2b, c1w, c1b, c2w, c2b, c3w, c3b, out);
}

// Round 2
// 697.825 us; speedup vs baseline: 1.9506x; 1.9506x over previous
//
#include <hip/hip_runtime.h>
#include <hip/hip_bf16.h>

#define N_NODES 100000
#define N_EDGES 1600000
#define ETOT    (N_EDGES + N_NODES)   // edges + self loops = 1,700,000
#define NE3     (3 * ETOT)
#define NF      256
#define NG      512
#define NHC     64                    // H*C
#define NOUT3   192                   // 3 views * 64
#define BN_EPS  1e-5f
#define CAP     96                    // LDS e-cache entries per row

__device__ __forceinline__ unsigned fenc(float f){
  unsigned b = __float_as_uint(f);
  return (b & 0x80000000u) ? ~b : (b | 0x80000000u);
}
__device__ __forceinline__ float fdec(unsigned u){
  unsigned b = (u & 0x80000000u) ? (u & 0x7FFFFFFFu) : ~u;
  return __uint_as_float(b);
}
__device__ __forceinline__ float lrelu(float x){ return x > 0.f ? x : 0.2f * x; }
__device__ __forceinline__ float eluf(float x){ return x > 0.f ? x : (__expf(x) - 1.f); }

// ---------------- init pooled to encoded -inf ----------------
__global__ void k_init_pooled(unsigned* pooled){
  int i = blockIdx.x * 256 + threadIdx.x;
  if (i < 3 * NG * NHC) pooled[i] = 0x007FFFFFu;   // fenc(-inf)
}

// ---------------- column stats of x ----------------
__global__ __launch_bounds__(256) void k_stats(const float* __restrict__ x,
                                               float* __restrict__ sums,
                                               float* __restrict__ sumsq){
  int t = threadIdx.x;
  int r0 = blockIdx.x * 128;
  int rmax = N_NODES - r0; if (rmax > 128) rmax = 128;
  float s = 0.f, q = 0.f;
  for (int r = 0; r < rmax; ++r){
    float v = x[(size_t)(r0 + r) * NF + t];
    s += v; q += v * v;
  }
  atomicAdd(&sums[t], s);
  atomicAdd(&sumsq[t], q);
}

// ---------------- fold BN into combined weight W' (256x192) and bias b' ----------------
__global__ __launch_bounds__(256) void k_prep(const float* __restrict__ sums, const float* __restrict__ sumsq,
                                              const float* __restrict__ bn_w, const float* __restrict__ bn_b,
                                              const float* __restrict__ WA, const float* __restrict__ WC,
                                              const float* __restrict__ WP,
                                              float* __restrict__ Wp, float* __restrict__ bp){
  __shared__ float ssc[NF], ssh[NF];
  int t = threadIdx.x;
  float mu  = sums[t]  * (1.f / N_NODES);
  float var = sumsq[t] * (1.f / N_NODES) - mu * mu;
  float sc  = bn_w[t] * rsqrtf(var + BN_EPS);
  ssc[t] = sc;
  ssh[t] = bn_b[t] - mu * sc;
  __syncthreads();
  if (t < NOUT3){
    int v = t / 64, o = t % 64;
    const float* W = (v == 0) ? WA : (v == 1) ? WC : WP;
    float b = 0.f;
    for (int f = 0; f < NF; ++f){
      float w = W[f * 64 + o];
      Wp[f * NOUT3 + t] = w * ssc[f];
      b += ssh[f] * w;
    }
    bp[t] = b;
  }
}

// ---------------- fused: GEMM blocks + edge-histogram blocks ----------------
// GEMM: h_all = x @ W' + b'  (M=100000, K=256, N=192), blocks [0, GEMM_NB)
// COUNT: pw[i] = atomicAdd(&count[vd], 1), blocks [GEMM_NB, GEMM_NB+COUNT_NB)
#define BM 128
#define BN 192
#define BK 32
#define GEMM_NB  ((N_NODES + BM - 1) / BM)          // 782
#define CGRAIN   8
#define COUNT_NB ((NE3 + 256*CGRAIN - 1) / (256*CGRAIN))
__global__ __launch_bounds__(256) void k_fused(const float* __restrict__ x, const float* __restrict__ Wp,
                                               const float* __restrict__ bp, float* __restrict__ h_all,
                                               const int* __restrict__ eA, const int* __restrict__ eC,
                                               const int* __restrict__ eP,
                                               int* __restrict__ count, int* __restrict__ pw){
  __shared__ float xs[BK][BM];
  __shared__ float ws_[BK][BN];
  int t = threadIdx.x;
  if (blockIdx.x >= GEMM_NB){
    // -------- histogram path: 1 atomic per edge, keep the returned position --------
    int base = (blockIdx.x - GEMM_NB) * (256 * CGRAIN) + t;
#pragma unroll
    for (int k = 0; k < CGRAIN; ++k){
      int i = base + k * 256;
      if (i < NE3){
        int v = i / ETOT; int j = i - v * ETOT;
        const int* ei = (v == 0) ? eA : (v == 1) ? eC : eP;
        int d = (j < N_EDGES) ? ei[N_EDGES + j] : (j - N_EDGES);
        int vd = v * N_NODES + d;
        pw[i] = atomicAdd(&count[vd], 1);
      }
    }
    return;
  }
  // -------- GEMM path --------
  int m0 = blockIdx.x * BM;
  int tc = (t & 15) * 12;
  int tr = (t >> 4) * 8;
  float acc[8][12];
#pragma unroll
  for (int i = 0; i < 8; ++i)
#pragma unroll
    for (int j = 0; j < 12; ++j) acc[i][j] = 0.f;

  int lrow = t >> 1;
  int lkh  = (t & 1) * 16;
  int grow = m0 + lrow; if (grow >= N_NODES) grow = N_NODES - 1;
  int wrow = t >> 3;
  int wc4  = (t & 7) * 6;

  for (int kc = 0; kc < NF; kc += BK){
    const float4* xsrc = (const float4*)(x + (size_t)grow * NF + kc + lkh);
    float4 a0 = xsrc[0], a1 = xsrc[1], a2 = xsrc[2], a3 = xsrc[3];
    const float4* wsrc = (const float4*)(Wp + (size_t)(kc + wrow) * BN);
    float4 b0 = wsrc[wc4+0], b1 = wsrc[wc4+1], b2 = wsrc[wc4+2],
           b3 = wsrc[wc4+3], b4 = wsrc[wc4+4], b5 = wsrc[wc4+5];
    __syncthreads();   // previous compute done before overwrite
    xs[lkh+ 0][lrow]=a0.x; xs[lkh+ 1][lrow]=a0.y; xs[lkh+ 2][lrow]=a0.z; xs[lkh+ 3][lrow]=a0.w;
    xs[lkh+ 4][lrow]=a1.x; xs[lkh+ 5][lrow]=a1.y; xs[lkh+ 6][lrow]=a1.z; xs[lkh+ 7][lrow]=a1.w;
    xs[lkh+ 8][lrow]=a2.x; xs[lkh+ 9][lrow]=a2.y; xs[lkh+10][lrow]=a2.z; xs[lkh+11][lrow]=a2.w;
    xs[lkh+12][lrow]=a3.x; xs[lkh+13][lrow]=a3.y; xs[lkh+14][lrow]=a3.z; xs[lkh+15][lrow]=a3.w;
    float4* wdst = (float4*)&ws_[wrow][0];
    wdst[wc4+0]=b0; wdst[wc4+1]=b1; wdst[wc4+2]=b2; wdst[wc4+3]=b3; wdst[wc4+4]=b4; wdst[wc4+5]=b5;
    __syncthreads();
#pragma unroll
    for (int k = 0; k < BK; ++k){
      float xv[8], wv[12];
      *(float4*)&xv[0] = *(const float4*)&xs[k][tr];
      *(float4*)&xv[4] = *(const float4*)&xs[k][tr+4];
      *(float4*)&wv[0] = *(const float4*)&ws_[k][tc];
      *(float4*)&wv[4] = *(const float4*)&ws_[k][tc+4];
      *(float4*)&wv[8] = *(const float4*)&ws_[k][tc+8];
#pragma unroll
      for (int i2 = 0; i2 < 8; ++i2)
#pragma unroll
        for (int j2 = 0; j2 < 12; ++j2)
          acc[i2][j2] += xv[i2] * wv[j2];
    }
  }
#pragma unroll
  for (int i2 = 0; i2 < 8; ++i2){
    int gr = m0 + tr + i2;
    if (gr < N_NODES){
      float* dst = h_all + (size_t)gr * BN + tc;
#pragma unroll
      for (int j2 = 0; j2 < 12; ++j2) dst[j2] = acc[i2][j2] + bp[tc + j2];
    }
  }
}

// ---------------- per (node,view,head) attention logits ----------------
__global__ __launch_bounds__(256) void k_att(const float* __restrict__ h_all,
                                             const float* __restrict__ asA, const float* __restrict__ adA,
                                             const float* __restrict__ asC, const float* __restrict__ adC,
                                             const float* __restrict__ asP, const float* __restrict__ adP,
                                             float* __restrict__ a_src, float* __restrict__ a_dst){
  int t = blockIdx.x * 256 + threadIdx.x;
  int g = t >> 4; int lid = t & 15;
  if (g >= 3 * N_NODES) return;
  int v = g / N_NODES; int n = g - v * N_NODES;
  const float* As = (v == 0) ? asA : (v == 1) ? asC : asP;
  const float* Ad = (v == 0) ? adA : (v == 1) ? adC : adP;
  float4 hv = *(const float4*)(h_all + (size_t)n * NOUT3 + v * 64 + lid * 4);
  float4 s4 = *(const float4*)(As + lid * 4);
  float4 d4 = *(const float4*)(Ad + lid * 4);
  float rs = hv.x*s4.x + hv.y*s4.y + hv.z*s4.z + hv.w*s4.w;
  float rd = hv.x*d4.x + hv.y*d4.y + hv.z*d4.z + hv.w*d4.w;
  rs += __shfl_xor(rs, 1); rd += __shfl_xor(rd, 1);
  rs += __shfl_xor(rs, 2); rd += __shfl_xor(rd, 2);
  rs += __shfl_xor(rs, 4); rd += __shfl_xor(rd, 4);
  if ((lid & 7) == 0){
    int h = lid >> 3;
    a_src[g * 2 + h] = rs;
    a_dst[g * 2 + h] = rd;
  }
}

// ---------------- exclusive scan (3 phases) ----------------
__global__ __launch_bounds__(256) void k_scan1(const int* __restrict__ cnt, int* __restrict__ out,
                                               int* __restrict__ bsum, int n){
  __shared__ int sh[256];
  int t = threadIdx.x; int base = blockIdx.x * 1024 + t * 4;
  int v0 = (base+0 < n) ? cnt[base+0] : 0;
  int v1 = (base+1 < n) ? cnt[base+1] : 0;
  int v2 = (base+2 < n) ? cnt[base+2] : 0;
  int v3 = (base+3 < n) ? cnt[base+3] : 0;
  int s = v0 + v1 + v2 + v3;
  sh[t] = s; __syncthreads();
  for (int off = 1; off < 256; off <<= 1){
    int xv = (t >= off) ? sh[t - off] : 0;
    __syncthreads();
    sh[t] += xv;
    __syncthreads();
  }
  int p = sh[t] - s;
  if (t == 255) bsum[blockIdx.x] = sh[255];
  if (base+0 < n){ out[base+0] = p; p += v0; }
  if (base+1 < n){ out[base+1] = p; p += v1; }
  if (base+2 < n){ out[base+2] = p; p += v2; }
  if (base+3 < n){ out[base+3] = p; }
}

__global__ __launch_bounds__(512) void k_scan2(int* __restrict__ bsum, int* __restrict__ total_out, int nb){
  __shared__ int sh[512];
  int t = threadIdx.x;
  int o = (t < nb) ? bsum[t] : 0;
  sh[t] = o; __syncthreads();
  for (int off = 1; off < 512; off <<= 1){
    int xv = (t >= off) ? sh[t - off] : 0;
    __syncthreads();
    sh[t] += xv;
    __syncthreads();
  }
  if (t < nb) bsum[t] = sh[t] - o;
  if (t == nb - 1) total_out[0] = sh[t];
}

__global__ __launch_bounds__(256) void k_scan3(int* __restrict__ out, const int* __restrict__ bsum, int n){
  int add = bsum[blockIdx.x];
  int base = blockIdx.x * 1024 + threadIdx.x * 4;
  if (base+0 < n) out[base+0] += add;
  if (base+1 < n) out[base+1] += add;
  if (base+2 < n) out[base+2] += add;
  if (base+3 < n) out[base+3] += add;
}

// ---------------- CSR placement: no atomics, uses stored pw ----------------
#define PGRAIN 4
__global__ __launch_bounds__(256) void k_place(const int* __restrict__ eA, const int* __restrict__ eC,
                                               const int* __restrict__ eP,
                                               const int* __restrict__ offsets, const int* __restrict__ pw,
                                               int* __restrict__ entries){
  int base = blockIdx.x * (256 * PGRAIN) + threadIdx.x;
#pragma unroll
  for (int k = 0; k < PGRAIN; ++k){
    int i = base + k * 256;
    if (i < NE3){
      int v = i / ETOT; int j = i - v * ETOT;
      const int* ei = (v == 0) ? eA : (v == 1) ? eC : eP;
      int s, d;
      if (j < N_EDGES){ s = ei[j]; d = ei[N_EDGES + j]; } else { s = j - N_EDGES; d = s; }
      int vd = v * N_NODES + d;
      entries[offsets[vd] + pw[i]] = s;
    }
  }
}

// ---------------- gather: two-pass row softmax + aggregate + elu + graph max-pool ----------------
__global__ __launch_bounds__(256) void k_gather(const int* __restrict__ entries, const int* __restrict__ offsets,
                                                const float* __restrict__ a_src, const float* __restrict__ a_dst,
                                                const float* __restrict__ h_all,
                                                const float* __restrict__ bA, const float* __restrict__ bC,
                                                const float* __restrict__ bP,
                                                const int* __restrict__ batch, unsigned* __restrict__ pooled){
  __shared__ float ec0[16][CAP];
  __shared__ float ec1[16][CAP];
  __shared__ int   sc[16][CAP];
  __shared__ unsigned red[64];
  __shared__ int kmin, kmax;
  int t = threadIdx.x;
  if (t == 0){ kmin = 0x7FFFFFFF; kmax = -1; }
  if (t < 64) red[t] = 0u;
  __syncthreads();
  int grp = t >> 4;
  int lid = t & 15;
  int g = blockIdx.x * 16 + grp;        // grid exact: 3N/16 blocks
  int v = g / N_NODES; int n = g - v * N_NODES;
  int vN = v * N_NODES;
  float ad0 = a_dst[g*2+0], ad1 = a_dst[g*2+1];
  int beg = offsets[g], end = offsets[g+1];
  int len = end - beg;
  // pass 1: parallel over entries — compute e, cache in LDS, running max
  float m0 = -1e30f, m1 = -1e30f;
  for (int idx = lid; idx < len; idx += 16){
    int s = entries[beg + idx];
    const float* ap = a_src + (size_t)(vN + s) * 2;
    float e0 = lrelu(ap[0] + ad0);
    float e1 = lrelu(ap[1] + ad1);
    if (idx < CAP){ sc[grp][idx] = s; ec0[grp][idx] = e0; ec1[grp][idx] = e1; }
    m0 = fmaxf(m0, e0); m1 = fmaxf(m1, e1);
  }
#pragma unroll
  for (int msk = 1; msk < 16; msk <<= 1){
    m0 = fmaxf(m0, __shfl_xor(m0, msk));
    m1 = fmaxf(m1, __shfl_xor(m1, msk));
  }
  __syncthreads();
  // pass 2: serial over entries, lanes own 4 output columns each
  float ax = 0.f, ay = 0.f, az = 0.f, aw = 0.f;
  float den0 = 0.f, den1 = 0.f;
  const float* hbase = h_all + v * 64 + lid * 4;
  for (int idx = 0; idx < len; ++idx){
    int s; float e0, e1;
    if (idx < CAP){
      s = sc[grp][idx]; e0 = ec0[grp][idx]; e1 = ec1[grp][idx];
    } else {
      s = entries[beg + idx];
      const float* ap = a_src + (size_t)(vN + s) * 2;
      e0 = lrelu(ap[0] + ad0); e1 = lrelu(ap[1] + ad1);
    }
    float p0 = __expf(e0 - m0), p1 = __expf(e1 - m1);
    den0 += p0; den1 += p1;
    float4 hv = *(const float4*)(hbase + (size_t)s * NOUT3);
    float ph = (lid < 8) ? p0 : p1;
    ax += ph * hv.x; ay += ph * hv.y; az += ph * hv.z; aw += ph * hv.w;
  }
  float den = ((lid < 8) ? den0 : den1) + 1e-16f;
  const float* bias = (v == 0) ? bA : (v == 1) ? bC : bP;
  float4 b4 = *(const float4*)(bias + lid * 4);
  unsigned e0u = fenc(eluf(ax / den + b4.x));
  unsigned e1u = fenc(eluf(ay / den + b4.y));
  unsigned e2u = fenc(eluf(az / den + b4.z));
  unsigned e3u = fenc(eluf(aw / den + b4.w));
  int key = v * NG + batch[n];
  if (lid == 0){ atomicMin(&kmin, key); atomicMax(&kmax, key); }
  atomicMax(&red[lid*4+0], e0u); atomicMax(&red[lid*4+1], e1u);
  atomicMax(&red[lid*4+2], e2u); atomicMax(&red[lid*4+3], e3u);
  __syncthreads();
  if (kmin == kmax){
    if (t < 64) atomicMax(&pooled[(size_t)kmin * 64 + t], red[t]);
  } else {
    unsigned* pp = pooled + (size_t)key * 64 + lid * 4;
    atomicMax(pp+0, e0u); atomicMax(pp+1, e1u); atomicMax(pp+2, e2u); atomicMax(pp+3, e3u);
  }
}

// ---------------- head MLP: one wave per graph ----------------
__global__ __launch_bounds__(64) void k_head(const unsigned* __restrict__ pooled,
                                             const float* __restrict__ g1w, const float* __restrict__ g1b,
                                             const float* __restrict__ g2w, const float* __restrict__ g2b,
                                             const float* __restrict__ c1w, const float* __restrict__ c1b,
                                             const float* __restrict__ c2w, const float* __restrict__ c2b,
                                             const float* __restrict__ c3w, const float* __restrict__ c3b,
                                             float* __restrict__ out){
  __shared__ float s1[64];
  __shared__ float s2[128];
  __shared__ float sw[3];
  int g = blockIdx.x, l = threadIdx.x;
  float ha = fdec(pooled[(size_t)g * 64 + l]);
  float hc = fdec(pooled[(size_t)(NG + g) * 64 + l]);
  float hp = fdec(pooled[(size_t)(2 * NG + g) * 64 + l]);
  s1[l] = (ha + hc + hp) * (1.f / 3.f);
  __syncthreads();
  float r1 = 0.f;
  if (l < 32){
    r1 = g1b[l];
    for (int i = 0; i < 64; ++i) r1 += s1[i] * g1w[i * 32 + l];
    r1 = fmaxf(r1, 0.f);
  }
  __syncthreads();
  if (l < 32) s2[l] = r1;
  __syncthreads();
  if (l < 3){
    float tv = g2b[l];
    for (int i = 0; i < 32; ++i) tv += s2[i] * g2w[i * 3 + l];
    sw[l] = tv;
  }
  __syncthreads();
  float t0 = sw[0], t1 = sw[1], t2 = sw[2];
  float mx = fmaxf(t0, fmaxf(t1, t2));
  float w0 = __expf(t0 - mx), w1 = __expf(t1 - mx), w2 = __expf(t2 - mx);
  float wsum = w0 + w1 + w2;
  float fused = (w0 * ha + w1 * hc + w2 * hp) / wsum;
  __syncthreads();
  s1[l] = fused;
  __syncthreads();
  float za = c1b[l], zb = c1b[64 + l];
  for (int i = 0; i < 64; ++i){
    float f = s1[i];
    za += f * c1w[i * 128 + l];
    zb += f * c1w[i * 128 + 64 + l];
  }
  za = fmaxf(za, 0.f); zb = fmaxf(zb, 0.f);
  s2[l] = za; s2[64 + l] = zb;
  __syncthreads();
  float z2 = c2b[l];
  for (int i = 0; i < 128; ++i) z2 += s2[i] * c2w[i * 64 + l];
  z2 = fmaxf(z2, 0.f);
  float prod = z2 * c3w[l];
  for (int off = 32; off > 0; off >>= 1) prod += __shfl_down(prod, off);
  if (l == 0) out[g] = prod + c3b[0];
}

extern "C" void kernel_launch(void* const* d_in, const int* in_sizes, int n_in,
                              void* d_out, int out_size, void* d_ws, size_t ws_size,
                              hipStream_t stream){
  const float* x    = (const float*)d_in[0];
  const int* eA     = (const int*)d_in[1];
  const int* eC     = (const int*)d_in[2];
  const int* eP     = (const int*)d_in[3];
  const int* batch  = (const int*)d_in[4];
  const float* bn_w = (const float*)d_in[6];
  const float* bn_b = (const float*)d_in[7];
  const float* WA   = (const float*)d_in[8];
  const float* asA  = (const float*)d_in[9];
  const float* adA  = (const float*)d_in[10];
  const float* bA   = (const float*)d_in[11];
  const float* WC   = (const float*)d_in[12];
  const float* asC  = (const float*)d_in[13];
  const float* adC  = (const float*)d_in[14];
  const float* bC   = (const float*)d_in[15];
  const float* WP   = (const float*)d_in[16];
  const float* asP  = (const float*)d_in[17];
  const float* adP  = (const float*)d_in[18];
  const float* bP   = (const float*)d_in[19];
  const float* g1w  = (const float*)d_in[20];
  const float* g1b  = (const float*)d_in[21];
  const float* g2w  = (const float*)d_in[22];
  const float* g2b  = (const float*)d_in[23];
  const float* c1w  = (const float*)d_in[24];
  const float* c1b  = (const float*)d_in[25];
  const float* c2w  = (const float*)d_in[26];
  const float* c2b  = (const float*)d_in[27];
  const float* c3w  = (const float*)d_in[28];
  const float* c3b  = (const float*)d_in[29];
  float* out = (float*)d_out;

  char* wptr = (char*)d_ws;
  auto alloc = [&](size_t bytes) -> void* {
    void* p = (void*)wptr;
    wptr += (bytes + 255) & ~(size_t)255;
    return p;
  };
  float*    sums    = (float*)   alloc((size_t)NF * 4);
  float*    sumsq   = (float*)   alloc((size_t)NF * 4);
  int*      count   = (int*)     alloc((size_t)3 * N_NODES * 4);
  size_t zbytes = (size_t)(wptr - (char*)sums);          // contiguous zero region
  int*      offsets = (int*)     alloc(((size_t)3 * N_NODES + 1) * 4);
  float*    Wp      = (float*)   alloc((size_t)NF * NOUT3 * 4);
  float*    bp      = (float*)   alloc((size_t)NOUT3 * 4);
  float*    h_all   = (float*)   alloc((size_t)N_NODES * NOUT3 * 4);
  float*    a_src   = (float*)   alloc((size_t)3 * N_NODES * 2 * 4);
  float*    a_dst   = (float*)   alloc((size_t)3 * N_NODES * 2 * 4);
  int*      pw      = (int*)     alloc((size_t)NE3 * 4);
  int*      entries = (int*)     alloc((size_t)NE3 * 4);
  unsigned* pooled  = (unsigned*)alloc((size_t)3 * NG * NHC * 4);
  int*      bsum    = (int*)     alloc((size_t)1024 * 4);

  hipMemsetAsync(sums, 0, zbytes, stream);
  k_init_pooled<<<(3 * NG * NHC + 255) / 256, 256, 0, stream>>>(pooled);
  k_stats<<<(N_NODES + 127) / 128, 256, 0, stream>>>(x, sums, sumsq);
  k_prep<<<1, 256, 0, stream>>>(sums, sumsq, bn_w, bn_b, WA, WC, WP, Wp, bp);
  k_fused<<<GEMM_NB + COUNT_NB, 256, 0, stream>>>(x, Wp, bp, h_all, eA, eC, eP, count, pw);
  k_att<<<(3 * N_NODES * 16 + 255) / 256, 256, 0, stream>>>(h_all, asA, adA, asC, adC, asP, adP, a_src, a_dst);
  int n3 = 3 * N_NODES;
  int nb = (n3 + 1023) / 1024;
  k_scan1<<<nb, 256, 0, stream>>>(count, offsets, bsum, n3);
  k_scan2<<<1, 512, 0, stream>>>(bsum, offsets + n3, nb);
  k_scan3<<<nb, 256, 0, stream>>>(offsets, bsum, n3);
  k_place<<<(NE3 + 256*PGRAIN - 1) / (256*PGRAIN), 256, 0, stream>>>(eA, eC, eP, offsets, pw, entries);
  k_gather<<<n3 / 16, 256, 0, stream>>>(entries, offsets, a_src, a_dst, h_all, bA, bC, bP, batch, pooled);
  k_head<<<NG, 64, 0, stream>>>(pooled, g1w, g1b, g2w, g2b, c1w, c1b, c2w, c2b, c3w, c3b, out);
}

// Round 3
// 575.201 us; speedup vs baseline: 2.3664x; 1.2132x over previous
//
#include <hip/hip_runtime.h>
#include <hip/hip_bf16.h>
#include <hip/hip_fp16.h>

#define N_NODES 100000
#define N_EDGES 1600000
#define ETOT    (N_EDGES + N_NODES)   // edges + self loops = 1,700,000
#define NE3     (3 * ETOT)            // 5,100,000
#define N3      (3 * N_NODES)         // 300,000
#define NF      256
#define NG      512
#define NHC     64                    // H*C
#define NOUT3   192                   // 3 views * 64
#define BN_EPS  1e-5f
#define CAP     96                    // LDS e-cache entries per row

// bucket sort params
#define NBUCK   293                   // ceil(300000/1024)
#define NB1     512                   // level-1 blocks
#define EGRAIN  39
#define ECHUNK  (256 * EGRAIN)        // 9984 edges per level-1 block

__device__ __forceinline__ unsigned fenc(float f){
  unsigned b = __float_as_uint(f);
  return (b & 0x80000000u) ? ~b : (b | 0x80000000u);
}
__device__ __forceinline__ float fdec(unsigned u){
  unsigned b = (u & 0x80000000u) ? (u & 0x7FFFFFFFu) : ~u;
  return __uint_as_float(b);
}
__device__ __forceinline__ float lrelu(float x){ return x > 0.f ? x : 0.2f * x; }
__device__ __forceinline__ float eluf(float x){ return x > 0.f ? x : (__expf(x) - 1.f); }

// ---------------- init pooled to encoded -inf ----------------
__global__ void k_init_pooled(unsigned* pooled){
  int i = blockIdx.x * 256 + threadIdx.x;
  if (i < 3 * NG * NHC) pooled[i] = 0x007FFFFFu;   // fenc(-inf)
}

// ---------------- fused: column stats of x + level-1 edge histogram ----------------
#define STATS_NB ((N_NODES + 127) / 128)
__global__ __launch_bounds__(256) void k_pre(const float* __restrict__ x,
                                             float* __restrict__ sums, float* __restrict__ sumsq,
                                             const int* __restrict__ eA, const int* __restrict__ eC,
                                             const int* __restrict__ eP,
                                             int* __restrict__ gcounts){
  int t = threadIdx.x;
  if (blockIdx.x < STATS_NB){
    int r0 = blockIdx.x * 128;
    int rmax = N_NODES - r0; if (rmax > 128) rmax = 128;
    float s = 0.f, q = 0.f;
    for (int r = 0; r < rmax; ++r){
      float v = x[(size_t)(r0 + r) * NF + t];
      s += v; q += v * v;
    }
    atomicAdd(&sums[t], s);
    atomicAdd(&sumsq[t], q);
    return;
  }
  // level-1 histogram over buckets vd>>10
  __shared__ int hist[NBUCK];
  int bi = blockIdx.x - STATS_NB;
  for (int b = t; b < NBUCK; b += 256) hist[b] = 0;
  __syncthreads();
  int base = bi * ECHUNK + t;
#pragma unroll
  for (int k = 0; k < EGRAIN; ++k){
    int i = base + k * 256;
    if (i < NE3){
      int v = i / ETOT; int j = i - v * ETOT;
      const int* ei = (v == 0) ? eA : (v == 1) ? eC : eP;
      int d = (j < N_EDGES) ? ei[N_EDGES + j] : (j - N_EDGES);
      int vd = v * N_NODES + d;
      atomicAdd(&hist[vd >> 10], 1);
    }
  }
  __syncthreads();
  for (int b = t; b < NBUCK; b += 256) gcounts[b * NB1 + bi] = hist[b];
}

// ---------------- fold BN into combined weight W' (256x192) and bias b' ----------------
__global__ __launch_bounds__(256) void k_prep2(const float* __restrict__ sums, const float* __restrict__ sumsq,
                                               const float* __restrict__ bn_w, const float* __restrict__ bn_b,
                                               const float* __restrict__ WA, const float* __restrict__ WC,
                                               const float* __restrict__ WP,
                                               float* __restrict__ Wp, float* __restrict__ bp){
  __shared__ float red[256];
  int o = blockIdx.x;                 // 0..191
  int v = o >> 6, oc = o & 63;
  const float* W = (v == 0) ? WA : (v == 1) ? WC : WP;
  int f = threadIdx.x;
  float mu  = sums[f]  * (1.f / N_NODES);
  float var = sumsq[f] * (1.f / N_NODES) - mu * mu;
  float sc  = bn_w[f] * rsqrtf(var + BN_EPS);
  float sh_ = bn_b[f] - mu * sc;
  float w = W[f * 64 + oc];
  Wp[f * NOUT3 + o] = w * sc;
  red[f] = sh_ * w;
  __syncthreads();
  for (int off = 128; off > 0; off >>= 1){
    if (f < off) red[f] += red[f + off];
    __syncthreads();
  }
  if (f == 0) bp[o] = red[0];
}

// ---------------- exclusive scan (3 phases) ----------------
__global__ __launch_bounds__(256) void k_scan1(const int* __restrict__ cnt, int* __restrict__ out,
                                               int* __restrict__ bsum, int n){
  __shared__ int sh[256];
  int t = threadIdx.x; int base = blockIdx.x * 1024 + t * 4;
  int v0 = (base+0 < n) ? cnt[base+0] : 0;
  int v1 = (base+1 < n) ? cnt[base+1] : 0;
  int v2 = (base+2 < n) ? cnt[base+2] : 0;
  int v3 = (base+3 < n) ? cnt[base+3] : 0;
  int s = v0 + v1 + v2 + v3;
  sh[t] = s; __syncthreads();
  for (int off = 1; off < 256; off <<= 1){
    int xv = (t >= off) ? sh[t - off] : 0;
    __syncthreads();
    sh[t] += xv;
    __syncthreads();
  }
  int p = sh[t] - s;
  if (t == 255) bsum[blockIdx.x] = sh[255];
  if (base+0 < n){ out[base+0] = p; p += v0; }
  if (base+1 < n){ out[base+1] = p; p += v1; }
  if (base+2 < n){ out[base+2] = p; p += v2; }
  if (base+3 < n){ out[base+3] = p; }
}

__global__ __launch_bounds__(512) void k_scan2(int* __restrict__ bsum, int* __restrict__ total_out, int nb){
  __shared__ int sh[512];
  int t = threadIdx.x;
  int o = (t < nb) ? bsum[t] : 0;
  sh[t] = o; __syncthreads();
  for (int off = 1; off < 512; off <<= 1){
    int xv = (t >= off) ? sh[t - off] : 0;
    __syncthreads();
    sh[t] += xv;
    __syncthreads();
  }
  if (t < nb) bsum[t] = sh[t] - o;
  if (t == nb - 1) total_out[0] = sh[t];
}

__global__ __launch_bounds__(256) void k_scan3(int* __restrict__ out, const int* __restrict__ bsum, int n){
  int add = bsum[blockIdx.x];
  int base = blockIdx.x * 1024 + threadIdx.x * 4;
  if (base+0 < n) out[base+0] += add;
  if (base+1 < n) out[base+1] += add;
  if (base+2 < n) out[base+2] += add;
  if (base+3 < n) out[base+3] += add;
}

// ---------------- fused: GEMM + level-1 scatter (LDS cursors, no global atomics) ----------------
#define BM 128
#define BN 192
#define BK 32
#define GEMM_NB  ((N_NODES + BM - 1) / BM)          // 782
__global__ __launch_bounds__(256) void k_fused(const float* __restrict__ x, const float* __restrict__ Wp,
                                               const float* __restrict__ bp, __half* __restrict__ h16,
                                               const int* __restrict__ eA, const int* __restrict__ eC,
                                               const int* __restrict__ eP,
                                               const int* __restrict__ gscan, int* __restrict__ packed){
  union Smem {
    struct { float xs[BK][BM]; float ws[BK][BN]; } g;
    int pos[NBUCK];
  };
  __shared__ Smem sm;
  int t = threadIdx.x;
  if (blockIdx.x >= GEMM_NB){
    // -------- scatter path --------
    int bi = blockIdx.x - GEMM_NB;
    for (int b = t; b < NBUCK; b += 256) sm.pos[b] = gscan[b * NB1 + bi];
    __syncthreads();
    int base = bi * ECHUNK + t;
#pragma unroll
    for (int k = 0; k < EGRAIN; ++k){
      int i = base + k * 256;
      if (i < NE3){
        int v = i / ETOT; int j = i - v * ETOT;
        const int* ei = (v == 0) ? eA : (v == 1) ? eC : eP;
        int s, d;
        if (j < N_EDGES){ s = ei[j]; d = ei[N_EDGES + j]; } else { s = j - N_EDGES; d = s; }
        int vd = v * N_NODES + d;
        int p = atomicAdd(&sm.pos[vd >> 10], 1);   // LDS atomic
        packed[p] = s | ((vd & 1023) << 17);
      }
    }
    return;
  }
  // -------- GEMM path --------
  int m0 = blockIdx.x * BM;
  int tc = (t & 15) * 12;
  int tr = (t >> 4) * 8;
  float acc[8][12];
#pragma unroll
  for (int i = 0; i < 8; ++i)
#pragma unroll
    for (int j = 0; j < 12; ++j) acc[i][j] = 0.f;

  int lrow = t >> 1;
  int lkh  = (t & 1) * 16;
  int grow = m0 + lrow; if (grow >= N_NODES) grow = N_NODES - 1;
  int wrow = t >> 3;
  int wc4  = (t & 7) * 6;

  for (int kc = 0; kc < NF; kc += BK){
    const float4* xsrc = (const float4*)(x + (size_t)grow * NF + kc + lkh);
    float4 a0 = xsrc[0], a1 = xsrc[1], a2 = xsrc[2], a3 = xsrc[3];
    const float4* wsrc = (const float4*)(Wp + (size_t)(kc + wrow) * BN);
    float4 b0 = wsrc[wc4+0], b1 = wsrc[wc4+1], b2 = wsrc[wc4+2],
           b3 = wsrc[wc4+3], b4 = wsrc[wc4+4], b5 = wsrc[wc4+5];
    __syncthreads();   // previous compute done before overwrite
    sm.g.xs[lkh+ 0][lrow]=a0.x; sm.g.xs[lkh+ 1][lrow]=a0.y; sm.g.xs[lkh+ 2][lrow]=a0.z; sm.g.xs[lkh+ 3][lrow]=a0.w;
    sm.g.xs[lkh+ 4][lrow]=a1.x; sm.g.xs[lkh+ 5][lrow]=a1.y; sm.g.xs[lkh+ 6][lrow]=a1.z; sm.g.xs[lkh+ 7][lrow]=a1.w;
    sm.g.xs[lkh+ 8][lrow]=a2.x; sm.g.xs[lkh+ 9][lrow]=a2.y; sm.g.xs[lkh+10][lrow]=a2.z; sm.g.xs[lkh+11][lrow]=a2.w;
    sm.g.xs[lkh+12][lrow]=a3.x; sm.g.xs[lkh+13][lrow]=a3.y; sm.g.xs[lkh+14][lrow]=a3.z; sm.g.xs[lkh+15][lrow]=a3.w;
    float4* wdst = (float4*)&sm.g.ws[wrow][0];
    wdst[wc4+0]=b0; wdst[wc4+1]=b1; wdst[wc4+2]=b2; wdst[wc4+3]=b3; wdst[wc4+4]=b4; wdst[wc4+5]=b5;
    __syncthreads();
#pragma unroll
    for (int k = 0; k < BK; ++k){
      float xv[8], wv[12];
      *(float4*)&xv[0] = *(const float4*)&sm.g.xs[k][tr];
      *(float4*)&xv[4] = *(const float4*)&sm.g.xs[k][tr+4];
      *(float4*)&wv[0] = *(const float4*)&sm.g.ws[k][tc];
      *(float4*)&wv[4] = *(const float4*)&sm.g.ws[k][tc+4];
      *(float4*)&wv[8] = *(const float4*)&sm.g.ws[k][tc+8];
#pragma unroll
      for (int i2 = 0; i2 < 8; ++i2)
#pragma unroll
        for (int j2 = 0; j2 < 12; ++j2)
          acc[i2][j2] += xv[i2] * wv[j2];
    }
  }
#pragma unroll
  for (int i2 = 0; i2 < 8; ++i2){
    int gr = m0 + tr + i2;
    if (gr < N_NODES){
      __half* dst = h16 + (size_t)gr * NOUT3 + tc;
#pragma unroll
      for (int j2 = 0; j2 < 6; ++j2){
        float lo = acc[i2][j2*2]   + bp[tc + j2*2];
        float hi = acc[i2][j2*2+1] + bp[tc + j2*2+1];
        *(__half2*)(dst + j2*2) = __float22half2_rn(make_float2(lo, hi));
      }
    }
  }
}

// ---------------- level-2: per-bucket exact CSR build (LDS only) ----------------
__global__ __launch_bounds__(256) void k_build(const int* __restrict__ gscan, const int* __restrict__ packed,
                                               int* __restrict__ entries, int* __restrict__ offsets){
  __shared__ int hist2[1024];
  __shared__ int sh[256];
  int b = blockIdx.x, t = threadIdx.x;
  int base = gscan[b * NB1];
  int end  = (b == NBUCK - 1) ? NE3 : gscan[(b + 1) * NB1];
#pragma unroll
  for (int i = 0; i < 4; ++i) hist2[t * 4 + i] = 0;
  __syncthreads();
  for (int i = base + t; i < end; i += 256)
    atomicAdd(&hist2[(packed[i] >> 17) & 1023], 1);
  __syncthreads();
  int s0 = hist2[t*4], s1 = hist2[t*4+1], s2 = hist2[t*4+2], s3 = hist2[t*4+3];
  int tot = s0 + s1 + s2 + s3;
  sh[t] = tot; __syncthreads();
  for (int off = 1; off < 256; off <<= 1){
    int xv = (t >= off) ? sh[t - off] : 0;
    __syncthreads();
    sh[t] += xv;
    __syncthreads();
  }
  int p = sh[t] - tot;
  hist2[t*4]   = p;
  hist2[t*4+1] = p + s0;
  hist2[t*4+2] = p + s0 + s1;
  hist2[t*4+3] = p + s0 + s1 + s2;
  __syncthreads();
  // write offsets for this bucket's node range
#pragma unroll
  for (int i = 0; i < 4; ++i){
    int vd = (b << 10) + t * 4 + i;
    if (vd < N3) offsets[vd] = base + hist2[t*4+i];
  }
  if (b == NBUCK - 1 && t == 0) offsets[N3] = NE3;
  __syncthreads();
  // place (hist2 now = running cursors)
  for (int i = base + t; i < end; i += 256){
    int pk = packed[i];
    int low = (pk >> 17) & 1023;
    int pos = atomicAdd(&hist2[low], 1);
    entries[base + pos] = pk & 0x1FFFF;
  }
}

// ---------------- per (node,view,head) attention logits ----------------
__global__ __launch_bounds__(256) void k_att(const __half* __restrict__ h16,
                                             const float* __restrict__ asA, const float* __restrict__ adA,
                                             const float* __restrict__ asC, const float* __restrict__ adC,
                                             const float* __restrict__ asP, const float* __restrict__ adP,
                                             float* __restrict__ a_src, float* __restrict__ a_dst){
  int t = blockIdx.x * 256 + threadIdx.x;
  int g = t >> 4; int lid = t & 15;
  if (g >= N3) return;
  int v = g / N_NODES; int n = g - v * N_NODES;
  const float* As = (v == 0) ? asA : (v == 1) ? asC : asP;
  const float* Ad = (v == 0) ? adA : (v == 1) ? adC : adP;
  const __half2* hp = (const __half2*)(h16 + (size_t)n * NOUT3 + v * 64 + lid * 4);
  float2 fa = __half22float2(hp[0]);
  float2 fb = __half22float2(hp[1]);
  float4 s4 = *(const float4*)(As + lid * 4);
  float4 d4 = *(const float4*)(Ad + lid * 4);
  float rs = fa.x*s4.x + fa.y*s4.y + fb.x*s4.z + fb.y*s4.w;
  float rd = fa.x*d4.x + fa.y*d4.y + fb.x*d4.z + fb.y*d4.w;
  rs += __shfl_xor(rs, 1); rd += __shfl_xor(rd, 1);
  rs += __shfl_xor(rs, 2); rd += __shfl_xor(rd, 2);
  rs += __shfl_xor(rs, 4); rd += __shfl_xor(rd, 4);
  if ((lid & 7) == 0){
    int h = lid >> 3;
    a_src[g * 2 + h] = rs;
    a_dst[g * 2 + h] = rd;
  }
}

// ---------------- gather: two-pass row softmax + aggregate + elu + graph max-pool ----------------
__global__ __launch_bounds__(256) void k_gather(const int* __restrict__ entries, const int* __restrict__ offsets,
                                                const float* __restrict__ a_src, const float* __restrict__ a_dst,
                                                const __half* __restrict__ h16,
                                                const float* __restrict__ bA, const float* __restrict__ bC,
                                                const float* __restrict__ bP,
                                                const int* __restrict__ batch, unsigned* __restrict__ pooled){
  __shared__ float ec0[16][CAP];
  __shared__ float ec1[16][CAP];
  __shared__ int   sc[16][CAP];
  __shared__ unsigned red[64];
  __shared__ int kmin, kmax;
  int t = threadIdx.x;
  if (t == 0){ kmin = 0x7FFFFFFF; kmax = -1; }
  if (t < 64) red[t] = 0u;
  __syncthreads();
  int grp = t >> 4;
  int lid = t & 15;
  int g = blockIdx.x * 16 + grp;        // grid exact: 3N/16 blocks
  int v = g / N_NODES; int n = g - v * N_NODES;
  int vN = v * N_NODES;
  float ad0 = a_dst[g*2+0], ad1 = a_dst[g*2+1];
  int beg = offsets[g], end = offsets[g+1];
  int len = end - beg;
  // pass 1: parallel over entries — compute e, cache in LDS, running max
  float m0 = -1e30f, m1 = -1e30f;
  for (int idx = lid; idx < len; idx += 16){
    int s = entries[beg + idx];
    const float* ap = a_src + (size_t)(vN + s) * 2;
    float e0 = lrelu(ap[0] + ad0);
    float e1 = lrelu(ap[1] + ad1);
    if (idx < CAP){ sc[grp][idx] = s; ec0[grp][idx] = e0; ec1[grp][idx] = e1; }
    m0 = fmaxf(m0, e0); m1 = fmaxf(m1, e1);
  }
#pragma unroll
  for (int msk = 1; msk < 16; msk <<= 1){
    m0 = fmaxf(m0, __shfl_xor(m0, msk));
    m1 = fmaxf(m1, __shfl_xor(m1, msk));
  }
  __syncthreads();
  // pass 2: serial over entries, lanes own 4 output columns each
  float ax = 0.f, ay = 0.f, az = 0.f, aw = 0.f;
  float den0 = 0.f, den1 = 0.f;
  const __half* hbase = h16 + v * 64 + lid * 4;
  for (int idx = 0; idx < len; ++idx){
    int s; float e0, e1;
    if (idx < CAP){
      s = sc[grp][idx]; e0 = ec0[grp][idx]; e1 = ec1[grp][idx];
    } else {
      s = entries[beg + idx];
      const float* ap = a_src + (size_t)(vN + s) * 2;
      e0 = lrelu(ap[0] + ad0); e1 = lrelu(ap[1] + ad1);
    }
    float p0 = __expf(e0 - m0), p1 = __expf(e1 - m1);
    den0 += p0; den1 += p1;
    const __half2* hh = (const __half2*)(hbase + (size_t)s * NOUT3);
    float2 f1 = __half22float2(hh[0]);
    float2 f2 = __half22float2(hh[1]);
    float ph = (lid < 8) ? p0 : p1;
    ax += ph * f1.x; ay += ph * f1.y; az += ph * f2.x; aw += ph * f2.y;
  }
  float den = ((lid < 8) ? den0 : den1) + 1e-16f;
  const float* bias = (v == 0) ? bA : (v == 1) ? bC : bP;
  float4 b4 = *(const float4*)(bias + lid * 4);
  unsigned e0u = fenc(eluf(ax / den + b4.x));
  unsigned e1u = fenc(eluf(ay / den + b4.y));
  unsigned e2u = fenc(eluf(az / den + b4.z));
  unsigned e3u = fenc(eluf(aw / den + b4.w));
  int key = v * NG + batch[n];
  if (lid == 0){ atomicMin(&kmin, key); atomicMax(&kmax, key); }
  atomicMax(&red[lid*4+0], e0u); atomicMax(&red[lid*4+1], e1u);
  atomicMax(&red[lid*4+2], e2u); atomicMax(&red[lid*4+3], e3u);
  __syncthreads();
  if (kmin == kmax){
    if (t < 64) atomicMax(&pooled[(size_t)kmin * 64 + t], red[t]);
  } else {
    unsigned* pp = pooled + (size_t)key * 64 + lid * 4;
    atomicMax(pp+0, e0u); atomicMax(pp+1, e1u); atomicMax(pp+2, e2u); atomicMax(pp+3, e3u);
  }
}

// ---------------- head MLP: one wave per graph ----------------
__global__ __launch_bounds__(64) void k_head(const unsigned* __restrict__ pooled,
                                             const float* __restrict__ g1w, const float* __restrict__ g1b,
                                             const float* __restrict__ g2w, const float* __restrict__ g2b,
                                             const float* __restrict__ c1w, const float* __restrict__ c1b,
                                             const float* __restrict__ c2w, const float* __restrict__ c2b,
                                             const float* __restrict__ c3w, const float* __restrict__ c3b,
                                             float* __restrict__ out){
  __shared__ float s1[64];
  __shared__ float s2[128];
  __shared__ float sw[3];
  int g = blockIdx.x, l = threadIdx.x;
  float ha = fdec(pooled[(size_t)g * 64 + l]);
  float hc = fdec(pooled[(size_t)(NG + g) * 64 + l]);
  float hp = fdec(pooled[(size_t)(2 * NG + g) * 64 + l]);
  s1[l] = (ha + hc + hp) * (1.f / 3.f);
  __syncthreads();
  float r1 = 0.f;
  if (l < 32){
    r1 = g1b[l];
    for (int i = 0; i < 64; ++i) r1 += s1[i] * g1w[i * 32 + l];
    r1 = fmaxf(r1, 0.f);
  }
  __syncthreads();
  if (l < 32) s2[l] = r1;
  __syncthreads();
  if (l < 3){
    float tv = g2b[l];
    for (int i = 0; i < 32; ++i) tv += s2[i] * g2w[i * 3 + l];
    sw[l] = tv;
  }
  __syncthreads();
  float t0 = sw[0], t1 = sw[1], t2 = sw[2];
  float mx = fmaxf(t0, fmaxf(t1, t2));
  float w0 = __expf(t0 - mx), w1 = __expf(t1 - mx), w2 = __expf(t2 - mx);
  float wsum = w0 + w1 + w2;
  float fused = (w0 * ha + w1 * hc + w2 * hp) / wsum;
  __syncthreads();
  s1[l] = fused;
  __syncthreads();
  float za = c1b[l], zb = c1b[64 + l];
  for (int i = 0; i < 64; ++i){
    float f = s1[i];
    za += f * c1w[i * 128 + l];
    zb += f * c1w[i * 128 + 64 + l];
  }
  za = fmaxf(za, 0.f); zb = fmaxf(zb, 0.f);
  s2[l] = za; s2[64 + l] = zb;
  __syncthreads();
  float z2 = c2b[l];
  for (int i = 0; i < 128; ++i) z2 += s2[i] * c2w[i * 64 + l];
  z2 = fmaxf(z2, 0.f);
  float prod = z2 * c3w[l];
  for (int off = 32; off > 0; off >>= 1) prod += __shfl_down(prod, off);
  if (l == 0) out[g] = prod + c3b[0];
}

extern "C" void kernel_launch(void* const* d_in, const int* in_sizes, int n_in,
                              void* d_out, int out_size, void* d_ws, size_t ws_size,
                              hipStream_t stream){
  const float* x    = (const float*)d_in[0];
  const int* eA     = (const int*)d_in[1];
  const int* eC     = (const int*)d_in[2];
  const int* eP     = (const int*)d_in[3];
  const int* batch  = (const int*)d_in[4];
  const float* bn_w = (const float*)d_in[6];
  const float* bn_b = (const float*)d_in[7];
  const float* WA   = (const float*)d_in[8];
  const float* asA  = (const float*)d_in[9];
  const float* adA  = (const float*)d_in[10];
  const float* bA   = (const float*)d_in[11];
  const float* WC   = (const float*)d_in[12];
  const float* asC  = (const float*)d_in[13];
  const float* adC  = (const float*)d_in[14];
  const float* bC   = (const float*)d_in[15];
  const float* WP   = (const float*)d_in[16];
  const float* asP  = (const float*)d_in[17];
  const float* adP  = (const float*)d_in[18];
  const float* bP   = (const float*)d_in[19];
  const float* g1w  = (const float*)d_in[20];
  const float* g1b  = (const float*)d_in[21];
  const float* g2w  = (const float*)d_in[22];
  const float* g2b  = (const float*)d_in[23];
  const float* c1w  = (const float*)d_in[24];
  const float* c1b  = (const float*)d_in[25];
  const float* c2w  = (const float*)d_in[26];
  const float* c2b  = (const float*)d_in[27];
  const float* c3w  = (const float*)d_in[28];
  const float* c3b  = (const float*)d_in[29];
  float* out = (float*)d_out;

  char* wptr = (char*)d_ws;
  auto alloc = [&](size_t bytes) -> void* {
    void* p = (void*)wptr;
    wptr += (bytes + 255) & ~(size_t)255;
    return p;
  };
  float*    sums    = (float*)   alloc((size_t)NF * 4);
  float*    sumsq   = (float*)   alloc((size_t)NF * 4);
  size_t zbytes = (size_t)(wptr - (char*)sums);          // contiguous zero region
  int*      gcounts = (int*)     alloc((size_t)NBUCK * NB1 * 4);
  int*      gscan   = (int*)     alloc((size_t)NBUCK * NB1 * 4);
  int*      offsets = (int*)     alloc(((size_t)N3 + 1) * 4);
  float*    Wp      = (float*)   alloc((size_t)NF * NOUT3 * 4);
  float*    bp      = (float*)   alloc((size_t)NOUT3 * 4);
  __half*   h16     = (__half*)  alloc((size_t)N_NODES * NOUT3 * 2);
  float*    a_src   = (float*)   alloc((size_t)N3 * 2 * 4);
  float*    a_dst   = (float*)   alloc((size_t)N3 * 2 * 4);
  int*      packed  = (int*)     alloc((size_t)NE3 * 4);
  int*      entries = (int*)     alloc((size_t)NE3 * 4);
  unsigned* pooled  = (unsigned*)alloc((size_t)3 * NG * NHC * 4);
  int*      bsum    = (int*)     alloc((size_t)512 * 4);
  int*      scrtot  = (int*)     alloc((size_t)64 * 4);

  hipMemsetAsync(sums, 0, zbytes, stream);
  k_init_pooled<<<(3 * NG * NHC + 255) / 256, 256, 0, stream>>>(pooled);
  k_pre<<<STATS_NB + NB1, 256, 0, stream>>>(x, sums, sumsq, eA, eC, eP, gcounts);
  k_prep2<<<NOUT3, 256, 0, stream>>>(sums, sumsq, bn_w, bn_b, WA, WC, WP, Wp, bp);
  int n_sc = NBUCK * NB1;
  int nb_sc = (n_sc + 1023) / 1024;
  k_scan1<<<nb_sc, 256, 0, stream>>>(gcounts, gscan, bsum, n_sc);
  k_scan2<<<1, 512, 0, stream>>>(bsum, scrtot, nb_sc);
  k_scan3<<<nb_sc, 256, 0, stream>>>(gscan, bsum, n_sc);
  k_fused<<<GEMM_NB + NB1, 256, 0, stream>>>(x, Wp, bp, h16, eA, eC, eP, gscan, packed);
  k_att<<<(N3 * 16 + 255) / 256, 256, 0, stream>>>(h16, asA, adA, asC, adC, asP, adP, a_src, a_dst);
  k_build<<<NBUCK, 256, 0, stream>>>(gscan, packed, entries, offsets);
  k_gather<<<N3 / 16, 256, 0, stream>>>(entries, offsets, a_src, a_dst, h16, bA, bC, bP, batch, pooled);
  k_head<<<NG, 64, 0, stream>>>(pooled, g1w, g1b, g2w, g2b, c1w, c1b, c2w, c2b, c3w, c3b, out);
}